// Round 24
// baseline (208.606 us; speedup 1.0000x reference)
//
#include <hip/hip_runtime.h>
#include <math.h>

#define BIGF 1e10f
#define EPSF 1e-5f

typedef _Float16 f16;
typedef f16 f16x8 __attribute__((ext_vector_type(8)));
typedef float f32x4 __attribute__((ext_vector_type(4)));

static __device__ __forceinline__ f16x8 mk8(uint a, uint b, uint c, uint d) {
    union { uint u[4]; f16x8 v; } t;
    t.u[0] = a; t.u[1] = b; t.u[2] = c; t.u[3] = d;
    return t.v;
}

// ---------------------------------------------------------------------------
// prep_all = prepack + prepad (R23-verified, unchanged)
// ---------------------------------------------------------------------------
__global__ __launch_bounds__(256) void prep_all(
    const float* __restrict__ c1w,
    const float* __restrict__ bn1g, const float* __restrict__ bn1b,
    const float* __restrict__ bn1m, const float* __restrict__ bn1v,
    const float* __restrict__ blkw,
    const float* __restrict__ blkg, const float* __restrict__ blkb,
    const float* __restrict__ blkm, const float* __restrict__ blkv,
    f16* __restrict__ wB, f16* __restrict__ wB1,
    float* __restrict__ b3, float* __restrict__ b1,
    const float* __restrict__ x, f16* __restrict__ xph, f16* __restrict__ xpl)
{
    if (blockIdx.x >= 690) {               // ---- prepad part (verified) ----
        int idx = (blockIdx.x - 690) * 256 + threadIdx.x;
        if (idx >= 128 * 3 * 107 * 52) return;
        int cp = idx % 52;
        int r  = (idx / 52) % 107;
        int ic = (idx / (52 * 107)) % 3;
        int b  = idx / (52 * 107 * 3);
        int ir = r - 5;
        uint pk_h = 0u, pk_l = 0u;
        if ((unsigned)ir < 96u) {
            int c0i = 2 * cp - 3, c1i = 2 * cp - 2;
            const float* rowp = x + ((size_t)b * 3 + ic) * 9216 + ir * 96;
            float v0 = ((unsigned)c0i < 96u) ? rowp[c0i] : 0.f;
            float v1 = ((unsigned)c1i < 96u) ? rowp[c1i] : 0.f;
            f16 h0 = (f16)v0; f16 lo0 = (f16)(v0 - (float)h0);
            f16 h1 = (f16)v1; f16 lo1 = (f16)(v1 - (float)h1);
            union { f16 f[2]; uint u32; } ph, pl;
            ph.f[0] = h0;  ph.f[1] = h1;  pk_h = ph.u32;
            pl.f[0] = lo0; pl.f[1] = lo1; pk_l = pl.u32;
        }
        ((uint*)xph)[idx] = pk_h;
        ((uint*)xpl)[idx] = pk_l;
        return;
    }
    int idx = blockIdx.x * 256 + threadIdx.x;
    if (idx < 147456) {                    // conv3 weight frags (verified)
        int pos = idx;
        int j    = pos & 7;
        int lane = (pos >> 3) & 63;
        int rest = pos >> 9;               // (((layer*9+tap)*4+nt)*2+kf)
        int kf   = rest & 1;
        int r2   = rest >> 1;
        int ntl  = r2 & 3;
        int r3   = r2 >> 2;
        int tap  = r3 % 9;
        int layer= r3 / 9;
        int ic = kf * 32 + (lane >> 4) * 8 + j;
        int oc = ntl * 16 + (lane & 15);
        float s = blkg[layer * 64 + oc] * rsqrtf(blkv[layer * 64 + oc] + EPSF);
        float wv = blkw[(((size_t)layer * 64 + oc) * 64 + ic) * 9 + tap] * s;
        f16 h = (f16)wv;
        f16 lo = (f16)(wv - (float)h);
        int low9 = pos & 511;
        wB[(size_t)rest * 1024 + low9]       = h;
        wB[(size_t)rest * 1024 + 512 + low9] = lo;
    }
    int q = idx - 147456;
    if (q >= 0 && q < 24576) {             // conv1 frags: 6 DENSE passes
        int j = q & 7, lane = (q >> 3) & 63, rest = q >> 9;  // ((p*4+nt)*2+hl)
        int hl = rest & 1, nt = (rest >> 1) & 3, p = rest >> 3;  // p 0..5
        int oc = nt * 16 + (lane & 15), lg = lane >> 4;
        int slot = p * 4 + lg;             // 0..23
        float v = 0.f;
        if (slot < 21 && j < 7) {
            int kh = slot / 3, ic = slot % 3;
            float s = bn1g[oc] * rsqrtf(bn1v[oc] + EPSF);
            v = c1w[((oc * 3 + ic) * 7 + kh) * 7 + j] * s;
        }
        f16 h = (f16)v;
        wB1[q] = hl ? (f16)(v - (float)h) : h;
    }
    int k = idx - 147456 - 24576;
    if (k >= 0 && k < 256) {
        float s = blkg[k] * rsqrtf(blkv[k] + EPSF);
        b3[k] = blkb[k] - blkm[k] * s;
    }
    int l = idx - 147456 - 24576 - 256;
    if (l >= 0 && l < 64) {
        float s = bn1g[l] * rsqrtf(bn1v[l] + EPSF);
        b1[l] = bn1b[l] - bn1m[l] * s;
    }
}

// ---------------------------------------------------------------------------
// conv1 v8 (R23-verified, unchanged): 6 dense k-slot passes, merged bh/bl.
// ---------------------------------------------------------------------------
__global__ __launch_bounds__(256) void conv1_mfma(
    const f16* __restrict__ xph, const f16* __restrict__ xpl,
    const f16* __restrict__ wB1, const float* __restrict__ bias,
    f16* __restrict__ outh, f16* __restrict__ outl)
{
    __shared__ char lds[18720];
    const int g = blockIdx.x, b = blockIdx.y;
    const int tid = threadIdx.x;
    const int w = tid >> 6, l = tid & 63;
    const int l15 = l & 15, lg = l >> 4;

    const int ir0 = 8 * g - 5;
#pragma unroll
    for (int i = 0; i < 5; ++i) {
        int ch = tid + i * 256;
        if (ch < 1170) {
            int arr = ch >= 585;
            int c2 = arr ? ch - 585 : ch;
            int ic = c2 / 195, rem = c2 - ic * 195;
            const f16* src = (arr ? xpl : xph) +
                ((size_t)(b * 3 + ic) * 107 + (ir0 + 5)) * 104 + rem * 8;
            *(uint4*)(lds + arr * 9360 + ic * 3120 + rem * 16) =
                *(const uint4*)(const void*)src;
        }
    }
    __syncthreads();

    f32x4 acc[4][4];
#pragma unroll
    for (int k = 0; k < 4; ++k)
#pragma unroll
        for (int nt = 0; nt < 4; ++nt) acc[k][nt] = (f32x4){0.f, 0.f, 0.f, 0.f};

    const f16* wq = wB1 + (size_t)l * 8;

    int rowoff[4], aoff[4];
#pragma unroll
    for (int k = 0; k < 4; ++k) {
        int t = w + 4 * k;
        int tt = (t < 15) ? t : 0;
        rowoff[k] = tt / 3;
        aoff[k] = 4 * ((tt % 3) * 16 + l15);
    }

#pragma unroll 1
    for (int p = 0; p < 6; ++p) {
        const f16* wk = wq + p * 4096;
        f16x8 bh[4], bl[4];
#pragma unroll
        for (int nt = 0; nt < 4; ++nt) {
            bh[nt] = *(const f16x8*)(const void*)(wk + nt * 1024);
            bl[nt] = *(const f16x8*)(const void*)(wk + nt * 1024 + 512);
        }
        int slot = p * 4 + lg;
        if (slot > 20) slot = 0;           // dead lanes: weights are zero
        const int kh = slot / 3;
        const int icb = (slot % 3) * 3120;
        const char* hb = lds + icb;
        const char* lb = lds + 9360 + icb;
#pragma unroll
        for (int k = 0; k < 4; ++k) {
            if (w + 4 * k < 15) {
                int ro = (2 * rowoff[k] + kh) * 208 + aoff[k];
                const uint* ph = (const uint*)(hb + ro);
                const uint* pl = (const uint*)(lb + ro);
                f16x8 ah = mk8(ph[0], ph[1], ph[2], ph[3]);
                f16x8 al = mk8(pl[0], pl[1], pl[2], pl[3]);
#pragma unroll
                for (int nt = 0; nt < 4; ++nt) {
                    acc[k][nt] = __builtin_amdgcn_mfma_f32_16x16x32_f16(ah, bh[nt], acc[k][nt], 0, 0, 0);
                    acc[k][nt] = __builtin_amdgcn_mfma_f32_16x16x32_f16(al, bh[nt], acc[k][nt], 0, 0, 0);
                    acc[k][nt] = __builtin_amdgcn_mfma_f32_16x16x32_f16(ah, bl[nt], acc[k][nt], 0, 0, 0);
                }
            }
        }
    }

    __syncthreads();
    float* pbuf = (float*)(void*)lds;
#pragma unroll
    for (int og = 0; og < 4; ++og) {
        float bi = bias[og * 16 + l15];
#pragma unroll
        for (int k = 0; k < 4; ++k) {
            int t = w + 4 * k;
            if (t < 15) {
                int lr = t / 3;
                int c0 = (t % 3) * 16;
#pragma unroll
                for (int r = 0; r < 4; ++r) {
                    int col = c0 + lg * 4 + r;
                    pbuf[(lr * 48 + col) * 17 + l15] = fmaxf(acc[k][og][r] + bi, 0.f);
                }
            }
        }
        __syncthreads();
#pragma unroll
        for (int it = 0; it < 3; ++it) {
            int idx = tid + it * 256;
            int oc = idx & 15, p2 = idx >> 4;
            int pc2 = p2 % 24, pr2 = p2 / 24;
            float m = -INFINITY;
#pragma unroll
            for (int kr = 0; kr < 3; ++kr) {
                int lr = 2 * pr2 + kr;
                if (g == 0 && lr == 0) continue;
#pragma unroll
                for (int kc = 0; kc < 3; ++kc) {
                    int cc = 2 * pc2 - 1 + kc;
                    if ((unsigned)cc < 48u)
                        m = fmaxf(m, pbuf[(lr * 48 + cc) * 17 + oc]);
                }
            }
            f16 h = (f16)m;
            f16 lo = (f16)(m - (float)h);
            size_t off = (size_t)b * 36864 +
                         (size_t)((2 * g + pr2) * 24 + pc2) * 64 + og * 16 + oc;
            outh[off] = h;
            outl[off] = lo;
        }
        __syncthreads();
    }
}

// ---------------------------------------------------------------------------
// conv3 (R15-verified, unchanged)
// ---------------------------------------------------------------------------
template<int MODE, int OUTT>
__global__ __launch_bounds__(256) void conv3_mfma(
    const f16* __restrict__ inh, const f16* __restrict__ inl,
    const f16* __restrict__ wB,
    const float* __restrict__ bias,
    const f16* __restrict__ resh, const f16* __restrict__ resl,
    f16* __restrict__ outh, f16* __restrict__ outl)
{
    __shared__ f16 lh[6 * 26 * 64];
    __shared__ f16 ll[6 * 26 * 64];
    const int r0 = blockIdx.x * 4;
    const int b  = blockIdx.y;
    const int tid = threadIdx.x;
    const int w = tid >> 6, l = tid & 63;
    const int l15 = l & 15, lg = l >> 4;

    if (tid < 192) {
        int arr = tid >= 96; int c2 = tid - arr * 96;
        int slot = c2 & 7; int pb = c2 >> 3;
        int lr = pb >> 1; int pc = (pb & 1) ? 25 : 0;
        int pix = lr * 26 + pc;
        int off = (pix * 128 + slot * 16) ^ ((pix & 7) << 4);
        *(uint4*)((arr ? (char*)ll : (char*)lh) + off) = make_uint4(0, 0, 0, 0);
    }
#pragma unroll
    for (int i = 0; i < 9; ++i) {
        int ch = tid + i * 256;
        int arr = ch >= 1152; int c2 = ch - arr * 1152;
        int slot = c2 & 7; int pix24 = c2 >> 3;
        int lr = pix24 / 24, pc = pix24 % 24;
        int ir = r0 - 1 + lr;
        uint4 v = make_uint4(0, 0, 0, 0);
        if ((unsigned)ir < 24u) {
            const f16* src = (arr ? inl : inh) +
                (((size_t)b * 576 + ir * 24 + pc) << 6) + slot * 8;
            v = *(const uint4*)(const void*)src;
        }
        int pix = lr * 26 + pc + 1;
        int off = (pix * 128 + slot * 16) ^ ((pix & 7) << 4);
        *(uint4*)((arr ? (char*)ll : (char*)lh) + off) = v;
    }

    int pr_[2], pc_[2];
#pragma unroll
    for (int mtl = 0; mtl < 2; ++mtl) {
        int t = w + 4 * mtl;
        int tt = (t < 6) ? t : 0;
        int lp = tt * 16 + l15;
        pr_[mtl] = lp / 24; pc_[mtl] = lp % 24;
    }

    f32x4 acc[2][4];
#pragma unroll
    for (int m = 0; m < 2; ++m)
#pragma unroll
        for (int n = 0; n < 4; ++n) acc[m][n] = (f32x4){0.f, 0.f, 0.f, 0.f};

    __syncthreads();

#pragma unroll 1
    for (int tap = 0; tap < 9; ++tap) {
        int dr = tap / 3, dc = tap % 3;
#pragma unroll
        for (int kf = 0; kf < 2; ++kf) {
            const f16* wb = wB + (size_t)tap * 8192 + (size_t)kf * 1024 + (size_t)l * 8;
            f16x8 bh[4], bl[4];
#pragma unroll
            for (int nt = 0; nt < 4; ++nt) {
                bh[nt] = *(const f16x8*)(const void*)(wb + nt * 2048);
                bl[nt] = *(const f16x8*)(const void*)(wb + nt * 2048 + 512);
            }
#pragma unroll
            for (int mtl = 0; mtl < 2; ++mtl) {
                if (mtl == 1 && w >= 2) continue;
                int pix = (pr_[mtl] + dr) * 26 + (pc_[mtl] + dc);
                int off = (pix * 128 + kf * 64 + lg * 16) ^ ((pix & 7) << 4);
                f16x8 ah = *(const f16x8*)((const char*)lh + off);
                f16x8 al = *(const f16x8*)((const char*)ll + off);
#pragma unroll
                for (int nt = 0; nt < 4; ++nt) {
                    acc[mtl][nt] = __builtin_amdgcn_mfma_f32_16x16x32_f16(ah, bh[nt], acc[mtl][nt], 0, 0, 0);
                    acc[mtl][nt] = __builtin_amdgcn_mfma_f32_16x16x32_f16(ah, bl[nt], acc[mtl][nt], 0, 0, 0);
                    acc[mtl][nt] = __builtin_amdgcn_mfma_f32_16x16x32_f16(al, bh[nt], acc[mtl][nt], 0, 0, 0);
                }
            }
        }
    }

    float bi[4];
#pragma unroll
    for (int nt = 0; nt < 4; ++nt) bi[nt] = bias[nt * 16 + l15];

#pragma unroll
    for (int mtl = 0; mtl < 2; ++mtl) {
        if (mtl == 1 && w >= 2) continue;
        int t = w + 4 * mtl;
#pragma unroll
        for (int nt = 0; nt < 4; ++nt) {
#pragma unroll
            for (int r = 0; r < 4; ++r) {
                int lp = t * 16 + lg * 4 + r;
                int p = r0 * 24 + lp;
                int oc = nt * 16 + l15;
                float v = acc[mtl][nt][r] + bi[nt];
                if (MODE) {
                    size_t ridx = (size_t)b * 36864 + (size_t)p * 64 + oc;
                    v += (float)resh[ridx] + (float)resl[ridx];
                }
                v = fmaxf(v, 0.f);
                f16 h = (f16)v;
                f16 lo = (f16)(v - (float)h);
                size_t oidx = OUTT ? ((size_t)b * 36864 + (size_t)oc * 576 + p)
                                   : ((size_t)b * 36864 + (size_t)p * 64 + oc);
                outh[oidx] = h;
                outl[oidx] = lo;
            }
        }
    }
}

// ---------------------------------------------------------------------------
// FC (R20-verified, unchanged): M-split grid 576, XCD swizzle, K-step 64.
// ---------------------------------------------------------------------------
#define FC_KSPLIT 32

__global__ __launch_bounds__(256) void fc_mfma(
    const f16* __restrict__ Ath, const f16* __restrict__ Atl,
    const float* __restrict__ Bw, float* __restrict__ part)
{
    __shared__ f16 As[2][64 * 72];
    __shared__ f16 Bs[2][16 * 72];
    const int bid = blockIdx.x;
    const int xcd = bid & 7, slot = bid >> 3;   // 0..71
    const int gi = slot / 18, rem = slot % 18;
    const int mh = rem / 9, nt = rem % 9;
    const int ks = gi * 8 + xcd;                // 0..31
    const int tid = threadIdx.x;
    const int w = tid >> 6, l = tid & 63;
    const int l15 = l & 15, lg = l >> 4;
    const int k0b = ks * 1152;
    const int mbase = mh * 64;

    f32x4 acc = (f32x4){0.f, 0.f, 0.f, 0.f};

    const int brow = tid >> 4, bk4 = (tid & 15) * 4;
#pragma unroll 1
    for (int st = 0; st < 18; ++st) {
        int k0 = k0b + st * 64;
        __syncthreads();
#pragma unroll
        for (int i = 0; i < 4; ++i) {
            int ch = tid + i * 256;
            int arr = ch >= 512; int c2 = ch - arr * 512;
            int m = c2 >> 3, slot8 = c2 & 7;
            const f16* src = (arr ? Atl : Ath) + (size_t)(mbase + m) * 36864 + k0 + slot8 * 8;
            *(uint4*)(void*)&As[arr][m * 72 + slot8 * 8] = *(const uint4*)(const void*)src;
        }
        {
            float4 f4 = *(const float4*)&Bw[(size_t)(nt * 16 + brow) * 36864 + k0 + bk4];
            f16 h0 = (f16)f4.x, h1 = (f16)f4.y, h2 = (f16)f4.z, h3 = (f16)f4.w;
            f16* bh = &Bs[0][brow * 72 + bk4];
            f16* bl = &Bs[1][brow * 72 + bk4];
            bh[0] = h0; bh[1] = h1; bh[2] = h2; bh[3] = h3;
            bl[0] = (f16)(f4.x - (float)h0);
            bl[1] = (f16)(f4.y - (float)h1);
            bl[2] = (f16)(f4.z - (float)h2);
            bl[3] = (f16)(f4.w - (float)h3);
        }
        __syncthreads();
#pragma unroll
        for (int kslot = 0; kslot < 2; ++kslot) {
            f16x8 bh = *(const f16x8*)(const void*)&Bs[0][l15 * 72 + kslot * 32 + lg * 8];
            f16x8 bl = *(const f16x8*)(const void*)&Bs[1][l15 * 72 + kslot * 32 + lg * 8];
            int m = w * 16 + l15;
            f16x8 ah = *(const f16x8*)(const void*)&As[0][m * 72 + kslot * 32 + lg * 8];
            f16x8 al = *(const f16x8*)(const void*)&As[1][m * 72 + kslot * 32 + lg * 8];
            acc = __builtin_amdgcn_mfma_f32_16x16x32_f16(ah, bh, acc, 0, 0, 0);
            acc = __builtin_amdgcn_mfma_f32_16x16x32_f16(ah, bl, acc, 0, 0, 0);
            acc = __builtin_amdgcn_mfma_f32_16x16x32_f16(al, bh, acc, 0, 0, 0);
        }
    }
#pragma unroll
    for (int r = 0; r < 4; ++r) {
        int m = mbase + w * 16 + lg * 4 + r;
        int n = nt * 16 + l15;
        part[((size_t)ks * 128 + m) * 144 + n] = acc[r];
    }
}

__global__ __launch_bounds__(256) void fc_reduce(
    const float* __restrict__ part, const float* __restrict__ bias,
    float* __restrict__ costs)
{
    int idx = blockIdx.x * 256 + threadIdx.x;
    if (idx >= 128 * 144) return;
    float sum = bias[idx % 144];
    for (int s = 0; s < FC_KSPLIT; ++s) sum += part[(size_t)s * (128 * 144) + idx];
    costs[idx] = sum;
}

// ---------------------------------------------------------------------------
// Bellman-Ford v8: SINGLE-WAVE block (64 thr), 3 cells/thread, fused 2-step
// relaxation (72 iters, R17-verified math). On a 1-wave block __syncthreads
// is near-free (no cross-wave rendezvous), and non-volatile LDS lets reads
// batch under one lgkmcnt wait (R14's volatile serialization avoided).
// ---------------------------------------------------------------------------
__global__ __launch_bounds__(64) void shortest_path(
    const float* __restrict__ costs, float* __restrict__ out)
{
    __shared__ float dP[2][256];   // [16][16], 2-wide BIG border
    __shared__ float cP[256];
    __shared__ float mask[144];
    const int b = blockIdx.x, tid = threadIdx.x;   // 0..63

    for (int k = tid; k < 256; k += 64) {
        dP[0][k] = BIGF; dP[1][k] = BIGF; cP[k] = BIGF;
    }
    for (int k = tid; k < 144; k += 64) mask[k] = 0.f;
    __syncthreads();

    const int m0 = tid, m1 = tid + 64, m2 = tid + 128;
    const bool has2 = (tid < 16);
    const int p0 = (m0 / 12 + 2) * 16 + (m0 % 12 + 2);
    const int p1 = (m1 / 12 + 2) * 16 + (m1 % 12 + 2);
    const int p2 = (m2 / 12 + 2) * 16 + (m2 % 12 + 2);

    const float* cpg = costs + b * 144;
    float c0v = cpg[m0];
    float c1v = cpg[m1];
    float c2v = has2 ? cpg[m2] : BIGF;
    cP[p0] = c0v;
    cP[p1] = c1v;
    if (has2) cP[p2] = c2v;
    if (tid == 0) dP[0][p0] = c0v;         // dist[0,0] = costs[0,0]
    __syncthreads();

    // per-cell neighbor costs (loop-invariant registers)
    float cU0 = cP[p0 - 16], cD0 = cP[p0 + 16], cL0 = cP[p0 - 1], cR0 = cP[p0 + 1];
    float cU1 = cP[p1 - 16], cD1 = cP[p1 + 16], cL1 = cP[p1 - 1], cR1 = cP[p1 + 1];
    float cU2 = BIGF, cD2 = BIGF, cL2 = BIGF, cR2 = BIGF;
    if (has2) { cU2 = cP[p2 - 16]; cD2 = cP[p2 + 16]; cL2 = cP[p2 - 1]; cR2 = cP[p2 + 1]; }

#define REL2(P, CS, CU, CD, CL, CR, OUTV)                                       \
    {                                                                           \
        float dS = cb[P];                                                       \
        float dU = cb[P - 16], dD = cb[P + 16], dL = cb[P - 1],  dR = cb[P + 1];\
        float dUU = cb[P - 32], dDD = cb[P + 32], dLL = cb[P - 2], dRR = cb[P + 2];\
        float dUL = cb[P - 17], dUR = cb[P - 15], dDL = cb[P + 15], dDR = cb[P + 17];\
        float ndU = fminf(dU, fminf(fminf(dUU, dS), fminf(dUL, dUR)) + CU);     \
        float ndD = fminf(dD, fminf(fminf(dS, dDD), fminf(dDL, dDR)) + CD);     \
        float ndL = fminf(dL, fminf(fminf(dUL, dDL), fminf(dLL, dS)) + CL);     \
        float ndR = fminf(dR, fminf(fminf(dUR, dDR), fminf(dS, dRR)) + CR);     \
        float ndS = fminf(dS, fminf(fminf(dU, dD), fminf(dL, dR)) + CS);        \
        OUTV = fminf(ndS, fminf(fminf(ndU, ndD), fminf(ndL, ndR)) + CS);        \
    }

    int cur = 0;
#pragma unroll 1
    for (int it = 0; it < 72; ++it) {      // 72 x 2 = 144 reference iters
        const float* cb = dP[cur];
        float o0, o1, o2 = BIGF;
        REL2(p0, c0v, cU0, cD0, cL0, cR0, o0)
        REL2(p1, c1v, cU1, cD1, cL1, cR1, o1)
        if (has2) REL2(p2, c2v, cU2, cD2, cL2, cR2, o2)
        float* nb = dP[cur ^ 1];
        nb[p0] = o0;
        nb[p1] = o1;
        if (has2) nb[p2] = o2;
        __syncthreads();                   // single-wave: near-free ordering
        cur ^= 1;
    }
#undef REL2

    if (tid == 0) {
        const float* fb = dP[cur];
        int pi = 11, pj = 11;
#pragma unroll 1
        for (int it = 0; it < 144; ++it) {
            mask[pi * 12 + pj] = 1.f;
            if (pi == 0 && pj == 0) break;
            int pp = (pi + 2) * 16 + (pj + 2);
            float vu = fb[pp - 16];
            float vd = fb[pp + 16];
            float vl = fb[pp - 1];
            float vr = fb[pp + 1];
            float best = vu; int kb = 0;   // first-min: up, down, left, right
            if (vd < best) { best = vd; kb = 1; }
            if (vl < best) { best = vl; kb = 2; }
            if (vr < best) { best = vr; kb = 3; }
            pi += (kb == 0) ? -1 : (kb == 1) ? 1 : 0;
            pj += (kb == 2) ? -1 : (kb == 3) ? 1 : 0;
        }
    }
    __syncthreads();
    out[b * 144 + m0] = mask[m0];
    out[b * 144 + m1] = mask[m1];
    if (has2) out[b * 144 + m2] = mask[m2];
}

// ---------------------------------------------------------------------------
extern "C" void kernel_launch(void* const* d_in, const int* in_sizes, int n_in,
                              void* d_out, int out_size, void* d_ws, size_t ws_size,
                              hipStream_t stream) {
    const float* x    = (const float*)d_in[0];
    const float* c1w  = (const float*)d_in[1];
    const float* bn1g = (const float*)d_in[2];
    const float* bn1b = (const float*)d_in[3];
    const float* bn1m = (const float*)d_in[4];
    const float* bn1v = (const float*)d_in[5];
    const float* blkw = (const float*)d_in[6];
    const float* blkg = (const float*)d_in[7];
    const float* blkb = (const float*)d_in[8];
    const float* blkm = (const float*)d_in[9];
    const float* blkv = (const float*)d_in[10];
    const float* fcw  = (const float*)d_in[11];
    const float* fcb  = (const float*)d_in[12];
    float* out = (float*)d_out;
    char* ws = (char*)d_ws;

    const size_t APL = 9437184;            // 128*36864 halves * 2B
    f16* a0h = (f16*)(ws);
    f16* a0l = (f16*)(ws + APL);
    f16* a1h = (f16*)(ws + 2 * APL);
    f16* a1l = (f16*)(ws + 3 * APL);
    f16* a2h = (f16*)(ws + 4 * APL);
    f16* a2l = (f16*)(ws + 5 * APL);
    float* costs = (float*)(ws + 6 * APL);                       // 73728 B
    float* part  = (float*)(ws + 6 * APL + 73728);               // 2359296 B
    f16*   wB    = (f16*)  (ws + 6 * APL + 73728 + 2359296);     // 589824 B
    float* b3    = (float*)(ws + 6 * APL + 73728 + 2359296 + 589824);       // 1024 B
    float* b1    = (float*)(ws + 6 * APL + 73728 + 2359296 + 589824 + 1024);// 256 B
    f16*   wB1   = (f16*)  (ws + 6 * APL + 73728 + 2359296 + 589824 + 1280);// 49152 B

    f16* xph = a1h;                        // prepadded planes (dead region)
    f16* xpl = a1l;

    prep_all<<<dim3(690 + 8346), dim3(256), 0, stream>>>(
        c1w, bn1g, bn1b, bn1m, bn1v, blkw, blkg, blkb, blkm, blkv,
        wB, wB1, b3, b1, x, xph, xpl);

    conv1_mfma<<<dim3(12, 128), dim3(256), 0, stream>>>(xph, xpl, wB1, b1, a0h, a0l);

    conv3_mfma<0, 0><<<dim3(6, 128), dim3(256), 0, stream>>>(
        a0h, a0l, wB + 0 * 73728, b3 + 0,   nullptr, nullptr, a1h, a1l);
    conv3_mfma<1, 0><<<dim3(6, 128), dim3(256), 0, stream>>>(
        a1h, a1l, wB + 1 * 73728, b3 + 64,  a0h, a0l, a2h, a2l);
    conv3_mfma<0, 0><<<dim3(6, 128), dim3(256), 0, stream>>>(
        a2h, a2l, wB + 2 * 73728, b3 + 128, nullptr, nullptr, a1h, a1l);
    conv3_mfma<1, 1><<<dim3(6, 128), dim3(256), 0, stream>>>(
        a1h, a1l, wB + 3 * 73728, b3 + 192, a2h, a2l, a0h, a0l);  // NCHW-T out

    fc_mfma<<<dim3(576), dim3(256), 0, stream>>>(a0h, a0l, fcw, part);
    fc_reduce<<<dim3(72), dim3(256), 0, stream>>>(part, fcb, costs);
    shortest_path<<<dim3(128), dim3(64), 0, stream>>>(costs, out);
}

// Round 25
// 201.858 us; speedup vs baseline: 1.0334x; 1.0334x over previous
//
#include <hip/hip_runtime.h>
#include <math.h>

#define BIGF 1e10f
#define EPSF 1e-5f

typedef _Float16 f16;
typedef f16 f16x8 __attribute__((ext_vector_type(8)));
typedef float f32x4 __attribute__((ext_vector_type(4)));

static __device__ __forceinline__ f16x8 mk8(uint a, uint b, uint c, uint d) {
    union { uint u[4]; f16x8 v; } t;
    t.u[0] = a; t.u[1] = b; t.u[2] = c; t.u[3] = d;
    return t.v;
}

// ---------------------------------------------------------------------------
// prep_all = prepack + prepad (R23-verified, unchanged)
// ---------------------------------------------------------------------------
__global__ __launch_bounds__(256) void prep_all(
    const float* __restrict__ c1w,
    const float* __restrict__ bn1g, const float* __restrict__ bn1b,
    const float* __restrict__ bn1m, const float* __restrict__ bn1v,
    const float* __restrict__ blkw,
    const float* __restrict__ blkg, const float* __restrict__ blkb,
    const float* __restrict__ blkm, const float* __restrict__ blkv,
    f16* __restrict__ wB, f16* __restrict__ wB1,
    float* __restrict__ b3, float* __restrict__ b1,
    const float* __restrict__ x, f16* __restrict__ xph, f16* __restrict__ xpl)
{
    if (blockIdx.x >= 690) {               // ---- prepad part (verified) ----
        int idx = (blockIdx.x - 690) * 256 + threadIdx.x;
        if (idx >= 128 * 3 * 107 * 52) return;
        int cp = idx % 52;
        int r  = (idx / 52) % 107;
        int ic = (idx / (52 * 107)) % 3;
        int b  = idx / (52 * 107 * 3);
        int ir = r - 5;
        uint pk_h = 0u, pk_l = 0u;
        if ((unsigned)ir < 96u) {
            int c0i = 2 * cp - 3, c1i = 2 * cp - 2;
            const float* rowp = x + ((size_t)b * 3 + ic) * 9216 + ir * 96;
            float v0 = ((unsigned)c0i < 96u) ? rowp[c0i] : 0.f;
            float v1 = ((unsigned)c1i < 96u) ? rowp[c1i] : 0.f;
            f16 h0 = (f16)v0; f16 lo0 = (f16)(v0 - (float)h0);
            f16 h1 = (f16)v1; f16 lo1 = (f16)(v1 - (float)h1);
            union { f16 f[2]; uint u32; } ph, pl;
            ph.f[0] = h0;  ph.f[1] = h1;  pk_h = ph.u32;
            pl.f[0] = lo0; pl.f[1] = lo1; pk_l = pl.u32;
        }
        ((uint*)xph)[idx] = pk_h;
        ((uint*)xpl)[idx] = pk_l;
        return;
    }
    int idx = blockIdx.x * 256 + threadIdx.x;
    if (idx < 147456) {                    // conv3 weight frags (verified)
        int pos = idx;
        int j    = pos & 7;
        int lane = (pos >> 3) & 63;
        int rest = pos >> 9;               // (((layer*9+tap)*4+nt)*2+kf)
        int kf   = rest & 1;
        int r2   = rest >> 1;
        int ntl  = r2 & 3;
        int r3   = r2 >> 2;
        int tap  = r3 % 9;
        int layer= r3 / 9;
        int ic = kf * 32 + (lane >> 4) * 8 + j;
        int oc = ntl * 16 + (lane & 15);
        float s = blkg[layer * 64 + oc] * rsqrtf(blkv[layer * 64 + oc] + EPSF);
        float wv = blkw[(((size_t)layer * 64 + oc) * 64 + ic) * 9 + tap] * s;
        f16 h = (f16)wv;
        f16 lo = (f16)(wv - (float)h);
        int low9 = pos & 511;
        wB[(size_t)rest * 1024 + low9]       = h;
        wB[(size_t)rest * 1024 + 512 + low9] = lo;
    }
    int q = idx - 147456;
    if (q >= 0 && q < 24576) {             // conv1 frags: 6 DENSE passes
        int j = q & 7, lane = (q >> 3) & 63, rest = q >> 9;  // ((p*4+nt)*2+hl)
        int hl = rest & 1, nt = (rest >> 1) & 3, p = rest >> 3;  // p 0..5
        int oc = nt * 16 + (lane & 15), lg = lane >> 4;
        int slot = p * 4 + lg;             // 0..23
        float v = 0.f;
        if (slot < 21 && j < 7) {
            int kh = slot / 3, ic = slot % 3;
            float s = bn1g[oc] * rsqrtf(bn1v[oc] + EPSF);
            v = c1w[((oc * 3 + ic) * 7 + kh) * 7 + j] * s;
        }
        f16 h = (f16)v;
        wB1[q] = hl ? (f16)(v - (float)h) : h;
    }
    int k = idx - 147456 - 24576;
    if (k >= 0 && k < 256) {
        float s = blkg[k] * rsqrtf(blkv[k] + EPSF);
        b3[k] = blkb[k] - blkm[k] * s;
    }
    int l = idx - 147456 - 24576 - 256;
    if (l >= 0 && l < 64) {
        float s = bn1g[l] * rsqrtf(bn1v[l] + EPSF);
        b1[l] = bn1b[l] - bn1m[l] * s;
    }
}

// ---------------------------------------------------------------------------
// conv1 v8 (R23-verified, unchanged): 6 dense k-slot passes, merged bh/bl.
// ---------------------------------------------------------------------------
__global__ __launch_bounds__(256) void conv1_mfma(
    const f16* __restrict__ xph, const f16* __restrict__ xpl,
    const f16* __restrict__ wB1, const float* __restrict__ bias,
    f16* __restrict__ outh, f16* __restrict__ outl)
{
    __shared__ char lds[18720];
    const int g = blockIdx.x, b = blockIdx.y;
    const int tid = threadIdx.x;
    const int w = tid >> 6, l = tid & 63;
    const int l15 = l & 15, lg = l >> 4;

    const int ir0 = 8 * g - 5;
#pragma unroll
    for (int i = 0; i < 5; ++i) {
        int ch = tid + i * 256;
        if (ch < 1170) {
            int arr = ch >= 585;
            int c2 = arr ? ch - 585 : ch;
            int ic = c2 / 195, rem = c2 - ic * 195;
            const f16* src = (arr ? xpl : xph) +
                ((size_t)(b * 3 + ic) * 107 + (ir0 + 5)) * 104 + rem * 8;
            *(uint4*)(lds + arr * 9360 + ic * 3120 + rem * 16) =
                *(const uint4*)(const void*)src;
        }
    }
    __syncthreads();

    f32x4 acc[4][4];
#pragma unroll
    for (int k = 0; k < 4; ++k)
#pragma unroll
        for (int nt = 0; nt < 4; ++nt) acc[k][nt] = (f32x4){0.f, 0.f, 0.f, 0.f};

    const f16* wq = wB1 + (size_t)l * 8;

    int rowoff[4], aoff[4];
#pragma unroll
    for (int k = 0; k < 4; ++k) {
        int t = w + 4 * k;
        int tt = (t < 15) ? t : 0;
        rowoff[k] = tt / 3;
        aoff[k] = 4 * ((tt % 3) * 16 + l15);
    }

#pragma unroll 1
    for (int p = 0; p < 6; ++p) {
        const f16* wk = wq + p * 4096;
        f16x8 bh[4], bl[4];
#pragma unroll
        for (int nt = 0; nt < 4; ++nt) {
            bh[nt] = *(const f16x8*)(const void*)(wk + nt * 1024);
            bl[nt] = *(const f16x8*)(const void*)(wk + nt * 1024 + 512);
        }
        int slot = p * 4 + lg;
        if (slot > 20) slot = 0;           // dead lanes: weights are zero
        const int kh = slot / 3;
        const int icb = (slot % 3) * 3120;
        const char* hb = lds + icb;
        const char* lb = lds + 9360 + icb;
#pragma unroll
        for (int k = 0; k < 4; ++k) {
            if (w + 4 * k < 15) {
                int ro = (2 * rowoff[k] + kh) * 208 + aoff[k];
                const uint* ph = (const uint*)(hb + ro);
                const uint* pl = (const uint*)(lb + ro);
                f16x8 ah = mk8(ph[0], ph[1], ph[2], ph[3]);
                f16x8 al = mk8(pl[0], pl[1], pl[2], pl[3]);
#pragma unroll
                for (int nt = 0; nt < 4; ++nt) {
                    acc[k][nt] = __builtin_amdgcn_mfma_f32_16x16x32_f16(ah, bh[nt], acc[k][nt], 0, 0, 0);
                    acc[k][nt] = __builtin_amdgcn_mfma_f32_16x16x32_f16(al, bh[nt], acc[k][nt], 0, 0, 0);
                    acc[k][nt] = __builtin_amdgcn_mfma_f32_16x16x32_f16(ah, bl[nt], acc[k][nt], 0, 0, 0);
                }
            }
        }
    }

    __syncthreads();
    float* pbuf = (float*)(void*)lds;
#pragma unroll
    for (int og = 0; og < 4; ++og) {
        float bi = bias[og * 16 + l15];
#pragma unroll
        for (int k = 0; k < 4; ++k) {
            int t = w + 4 * k;
            if (t < 15) {
                int lr = t / 3;
                int c0 = (t % 3) * 16;
#pragma unroll
                for (int r = 0; r < 4; ++r) {
                    int col = c0 + lg * 4 + r;
                    pbuf[(lr * 48 + col) * 17 + l15] = fmaxf(acc[k][og][r] + bi, 0.f);
                }
            }
        }
        __syncthreads();
#pragma unroll
        for (int it = 0; it < 3; ++it) {
            int idx = tid + it * 256;
            int oc = idx & 15, p2 = idx >> 4;
            int pc2 = p2 % 24, pr2 = p2 / 24;
            float m = -INFINITY;
#pragma unroll
            for (int kr = 0; kr < 3; ++kr) {
                int lr = 2 * pr2 + kr;
                if (g == 0 && lr == 0) continue;
#pragma unroll
                for (int kc = 0; kc < 3; ++kc) {
                    int cc = 2 * pc2 - 1 + kc;
                    if ((unsigned)cc < 48u)
                        m = fmaxf(m, pbuf[(lr * 48 + cc) * 17 + oc]);
                }
            }
            f16 h = (f16)m;
            f16 lo = (f16)(m - (float)h);
            size_t off = (size_t)b * 36864 +
                         (size_t)((2 * g + pr2) * 24 + pc2) * 64 + og * 16 + oc;
            outh[off] = h;
            outl[off] = lo;
        }
        __syncthreads();
    }
}

// ---------------------------------------------------------------------------
// conv3 (R15-verified, unchanged)
// ---------------------------------------------------------------------------
template<int MODE, int OUTT>
__global__ __launch_bounds__(256) void conv3_mfma(
    const f16* __restrict__ inh, const f16* __restrict__ inl,
    const f16* __restrict__ wB,
    const float* __restrict__ bias,
    const f16* __restrict__ resh, const f16* __restrict__ resl,
    f16* __restrict__ outh, f16* __restrict__ outl)
{
    __shared__ f16 lh[6 * 26 * 64];
    __shared__ f16 ll[6 * 26 * 64];
    const int r0 = blockIdx.x * 4;
    const int b  = blockIdx.y;
    const int tid = threadIdx.x;
    const int w = tid >> 6, l = tid & 63;
    const int l15 = l & 15, lg = l >> 4;

    if (tid < 192) {
        int arr = tid >= 96; int c2 = tid - arr * 96;
        int slot = c2 & 7; int pb = c2 >> 3;
        int lr = pb >> 1; int pc = (pb & 1) ? 25 : 0;
        int pix = lr * 26 + pc;
        int off = (pix * 128 + slot * 16) ^ ((pix & 7) << 4);
        *(uint4*)((arr ? (char*)ll : (char*)lh) + off) = make_uint4(0, 0, 0, 0);
    }
#pragma unroll
    for (int i = 0; i < 9; ++i) {
        int ch = tid + i * 256;
        int arr = ch >= 1152; int c2 = ch - arr * 1152;
        int slot = c2 & 7; int pix24 = c2 >> 3;
        int lr = pix24 / 24, pc = pix24 % 24;
        int ir = r0 - 1 + lr;
        uint4 v = make_uint4(0, 0, 0, 0);
        if ((unsigned)ir < 24u) {
            const f16* src = (arr ? inl : inh) +
                (((size_t)b * 576 + ir * 24 + pc) << 6) + slot * 8;
            v = *(const uint4*)(const void*)src;
        }
        int pix = lr * 26 + pc + 1;
        int off = (pix * 128 + slot * 16) ^ ((pix & 7) << 4);
        *(uint4*)((arr ? (char*)ll : (char*)lh) + off) = v;
    }

    int pr_[2], pc_[2];
#pragma unroll
    for (int mtl = 0; mtl < 2; ++mtl) {
        int t = w + 4 * mtl;
        int tt = (t < 6) ? t : 0;
        int lp = tt * 16 + l15;
        pr_[mtl] = lp / 24; pc_[mtl] = lp % 24;
    }

    f32x4 acc[2][4];
#pragma unroll
    for (int m = 0; m < 2; ++m)
#pragma unroll
        for (int n = 0; n < 4; ++n) acc[m][n] = (f32x4){0.f, 0.f, 0.f, 0.f};

    __syncthreads();

#pragma unroll 1
    for (int tap = 0; tap < 9; ++tap) {
        int dr = tap / 3, dc = tap % 3;
#pragma unroll
        for (int kf = 0; kf < 2; ++kf) {
            const f16* wb = wB + (size_t)tap * 8192 + (size_t)kf * 1024 + (size_t)l * 8;
            f16x8 bh[4], bl[4];
#pragma unroll
            for (int nt = 0; nt < 4; ++nt) {
                bh[nt] = *(const f16x8*)(const void*)(wb + nt * 2048);
                bl[nt] = *(const f16x8*)(const void*)(wb + nt * 2048 + 512);
            }
#pragma unroll
            for (int mtl = 0; mtl < 2; ++mtl) {
                if (mtl == 1 && w >= 2) continue;
                int pix = (pr_[mtl] + dr) * 26 + (pc_[mtl] + dc);
                int off = (pix * 128 + kf * 64 + lg * 16) ^ ((pix & 7) << 4);
                f16x8 ah = *(const f16x8*)((const char*)lh + off);
                f16x8 al = *(const f16x8*)((const char*)ll + off);
#pragma unroll
                for (int nt = 0; nt < 4; ++nt) {
                    acc[mtl][nt] = __builtin_amdgcn_mfma_f32_16x16x32_f16(ah, bh[nt], acc[mtl][nt], 0, 0, 0);
                    acc[mtl][nt] = __builtin_amdgcn_mfma_f32_16x16x32_f16(ah, bl[nt], acc[mtl][nt], 0, 0, 0);
                    acc[mtl][nt] = __builtin_amdgcn_mfma_f32_16x16x32_f16(al, bh[nt], acc[mtl][nt], 0, 0, 0);
                }
            }
        }
    }

    float bi[4];
#pragma unroll
    for (int nt = 0; nt < 4; ++nt) bi[nt] = bias[nt * 16 + l15];

#pragma unroll
    for (int mtl = 0; mtl < 2; ++mtl) {
        if (mtl == 1 && w >= 2) continue;
        int t = w + 4 * mtl;
#pragma unroll
        for (int nt = 0; nt < 4; ++nt) {
#pragma unroll
            for (int r = 0; r < 4; ++r) {
                int lp = t * 16 + lg * 4 + r;
                int p = r0 * 24 + lp;
                int oc = nt * 16 + l15;
                float v = acc[mtl][nt][r] + bi[nt];
                if (MODE) {
                    size_t ridx = (size_t)b * 36864 + (size_t)p * 64 + oc;
                    v += (float)resh[ridx] + (float)resl[ridx];
                }
                v = fmaxf(v, 0.f);
                f16 h = (f16)v;
                f16 lo = (f16)(v - (float)h);
                size_t oidx = OUTT ? ((size_t)b * 36864 + (size_t)oc * 576 + p)
                                   : ((size_t)b * 36864 + (size_t)p * 64 + oc);
                outh[oidx] = h;
                outl[oidx] = lo;
            }
        }
    }
}

// ---------------------------------------------------------------------------
// FC (R20-verified, unchanged): M-split grid 576, XCD swizzle, K-step 64.
// ---------------------------------------------------------------------------
#define FC_KSPLIT 32

__global__ __launch_bounds__(256) void fc_mfma(
    const f16* __restrict__ Ath, const f16* __restrict__ Atl,
    const float* __restrict__ Bw, float* __restrict__ part)
{
    __shared__ f16 As[2][64 * 72];
    __shared__ f16 Bs[2][16 * 72];
    const int bid = blockIdx.x;
    const int xcd = bid & 7, slot = bid >> 3;   // 0..71
    const int gi = slot / 18, rem = slot % 18;
    const int mh = rem / 9, nt = rem % 9;
    const int ks = gi * 8 + xcd;                // 0..31
    const int tid = threadIdx.x;
    const int w = tid >> 6, l = tid & 63;
    const int l15 = l & 15, lg = l >> 4;
    const int k0b = ks * 1152;
    const int mbase = mh * 64;

    f32x4 acc = (f32x4){0.f, 0.f, 0.f, 0.f};

    const int brow = tid >> 4, bk4 = (tid & 15) * 4;
#pragma unroll 1
    for (int st = 0; st < 18; ++st) {
        int k0 = k0b + st * 64;
        __syncthreads();
#pragma unroll
        for (int i = 0; i < 4; ++i) {
            int ch = tid + i * 256;
            int arr = ch >= 512; int c2 = ch - arr * 512;
            int m = c2 >> 3, slot8 = c2 & 7;
            const f16* src = (arr ? Atl : Ath) + (size_t)(mbase + m) * 36864 + k0 + slot8 * 8;
            *(uint4*)(void*)&As[arr][m * 72 + slot8 * 8] = *(const uint4*)(const void*)src;
        }
        {
            float4 f4 = *(const float4*)&Bw[(size_t)(nt * 16 + brow) * 36864 + k0 + bk4];
            f16 h0 = (f16)f4.x, h1 = (f16)f4.y, h2 = (f16)f4.z, h3 = (f16)f4.w;
            f16* bh = &Bs[0][brow * 72 + bk4];
            f16* bl = &Bs[1][brow * 72 + bk4];
            bh[0] = h0; bh[1] = h1; bh[2] = h2; bh[3] = h3;
            bl[0] = (f16)(f4.x - (float)h0);
            bl[1] = (f16)(f4.y - (float)h1);
            bl[2] = (f16)(f4.z - (float)h2);
            bl[3] = (f16)(f4.w - (float)h3);
        }
        __syncthreads();
#pragma unroll
        for (int kslot = 0; kslot < 2; ++kslot) {
            f16x8 bh = *(const f16x8*)(const void*)&Bs[0][l15 * 72 + kslot * 32 + lg * 8];
            f16x8 bl = *(const f16x8*)(const void*)&Bs[1][l15 * 72 + kslot * 32 + lg * 8];
            int m = w * 16 + l15;
            f16x8 ah = *(const f16x8*)(const void*)&As[0][m * 72 + kslot * 32 + lg * 8];
            f16x8 al = *(const f16x8*)(const void*)&As[1][m * 72 + kslot * 32 + lg * 8];
            acc = __builtin_amdgcn_mfma_f32_16x16x32_f16(ah, bh, acc, 0, 0, 0);
            acc = __builtin_amdgcn_mfma_f32_16x16x32_f16(ah, bl, acc, 0, 0, 0);
            acc = __builtin_amdgcn_mfma_f32_16x16x32_f16(al, bh, acc, 0, 0, 0);
        }
    }
#pragma unroll
    for (int r = 0; r < 4; ++r) {
        int m = mbase + w * 16 + lg * 4 + r;
        int n = nt * 16 + l15;
        part[((size_t)ks * 128 + m) * 144 + n] = acc[r];
    }
}

__global__ __launch_bounds__(256) void fc_reduce(
    const float* __restrict__ part, const float* __restrict__ bias,
    float* __restrict__ costs)
{
    int idx = blockIdx.x * 256 + threadIdx.x;
    if (idx >= 128 * 144) return;
    float sum = bias[idx % 144];
    for (int s = 0; s < FC_KSPLIT; ++s) sum += part[(size_t)s * (128 * 144) + idx];
    costs[idx] = sum;
}

// ---------------------------------------------------------------------------
// Bellman-Ford v7 (R17/R23-verified, best of 8 measured variants: ~27 us).
// 192 threads (3 waves), fused 2-step relaxation, 72 barriers.
// ---------------------------------------------------------------------------
__global__ __launch_bounds__(192) void shortest_path(
    const float* __restrict__ costs, float* __restrict__ out)
{
    __shared__ float dP[2][256];
    __shared__ float cP[256];
    __shared__ float mask[144];
    const int b = blockIdx.x, tid = threadIdx.x;

    if (tid < 128) {
        dP[0][tid] = BIGF; dP[0][tid + 128] = BIGF;
        dP[1][tid] = BIGF; dP[1][tid + 128] = BIGF;
        cP[tid] = BIGF;    cP[tid + 128] = BIGF;
    }
    if (tid < 144) mask[tid] = 0.f;
    __syncthreads();

    const int i = tid / 12, j = tid % 12;
    const int p = (i + 2) * 16 + (j + 2);
    if (tid < 144) {
        float c = costs[b * 144 + tid];
        cP[p] = c;
        if (tid == 0) dP[0][p] = c;
    }
    __syncthreads();

    float cS = 0.f, cU = 0.f, cD = 0.f, cL = 0.f, cR = 0.f;
    if (tid < 144) {
        cS = cP[p];
        cU = cP[p - 16]; cD = cP[p + 16];
        cL = cP[p - 1];  cR = cP[p + 1];
    }

    int cur = 0;
#pragma unroll 1
    for (int it = 0; it < 72; ++it) {
        if (tid < 144) {
            const float* cb = dP[cur];
            float dS = cb[p];
            float dU = cb[p - 16], dD = cb[p + 16], dL = cb[p - 1],  dR = cb[p + 1];
            float dUU = cb[p - 32], dDD = cb[p + 32], dLL = cb[p - 2], dRR = cb[p + 2];
            float dUL = cb[p - 17], dUR = cb[p - 15], dDL = cb[p + 15], dDR = cb[p + 17];
            float ndU = fminf(dU, fminf(fminf(dUU, dS), fminf(dUL, dUR)) + cU);
            float ndD = fminf(dD, fminf(fminf(dS, dDD), fminf(dDL, dDR)) + cD);
            float ndL = fminf(dL, fminf(fminf(dUL, dDL), fminf(dLL, dS)) + cL);
            float ndR = fminf(dR, fminf(fminf(dUR, dDR), fminf(dS, dRR)) + cR);
            float ndS = fminf(dS, fminf(fminf(dU, dD), fminf(dL, dR)) + cS);
            float d2 = fminf(ndS, fminf(fminf(ndU, ndD), fminf(ndL, ndR)) + cS);
            dP[cur ^ 1][p] = d2;
        }
        __syncthreads();
        cur ^= 1;
    }

    if (tid == 0) {
        const float* fb = dP[cur];
        int pi = 11, pj = 11;
#pragma unroll 1
        for (int it = 0; it < 144; ++it) {
            mask[pi * 12 + pj] = 1.f;
            if (pi == 0 && pj == 0) break;
            int pp = (pi + 2) * 16 + (pj + 2);
            float vu = fb[pp - 16];
            float vd = fb[pp + 16];
            float vl = fb[pp - 1];
            float vr = fb[pp + 1];
            float best = vu; int kb = 0;
            if (vd < best) { best = vd; kb = 1; }
            if (vl < best) { best = vl; kb = 2; }
            if (vr < best) { best = vr; kb = 3; }
            pi += (kb == 0) ? -1 : (kb == 1) ? 1 : 0;
            pj += (kb == 2) ? -1 : (kb == 3) ? 1 : 0;
        }
    }
    __syncthreads();
    if (tid < 144) out[b * 144 + tid] = mask[tid];
}

// ---------------------------------------------------------------------------
extern "C" void kernel_launch(void* const* d_in, const int* in_sizes, int n_in,
                              void* d_out, int out_size, void* d_ws, size_t ws_size,
                              hipStream_t stream) {
    const float* x    = (const float*)d_in[0];
    const float* c1w  = (const float*)d_in[1];
    const float* bn1g = (const float*)d_in[2];
    const float* bn1b = (const float*)d_in[3];
    const float* bn1m = (const float*)d_in[4];
    const float* bn1v = (const float*)d_in[5];
    const float* blkw = (const float*)d_in[6];
    const float* blkg = (const float*)d_in[7];
    const float* blkb = (const float*)d_in[8];
    const float* blkm = (const float*)d_in[9];
    const float* blkv = (const float*)d_in[10];
    const float* fcw  = (const float*)d_in[11];
    const float* fcb  = (const float*)d_in[12];
    float* out = (float*)d_out;
    char* ws = (char*)d_ws;

    const size_t APL = 9437184;            // 128*36864 halves * 2B
    f16* a0h = (f16*)(ws);
    f16* a0l = (f16*)(ws + APL);
    f16* a1h = (f16*)(ws + 2 * APL);
    f16* a1l = (f16*)(ws + 3 * APL);
    f16* a2h = (f16*)(ws + 4 * APL);
    f16* a2l = (f16*)(ws + 5 * APL);
    float* costs = (float*)(ws + 6 * APL);                       // 73728 B
    float* part  = (float*)(ws + 6 * APL + 73728);               // 2359296 B
    f16*   wB    = (f16*)  (ws + 6 * APL + 73728 + 2359296);     // 589824 B
    float* b3    = (float*)(ws + 6 * APL + 73728 + 2359296 + 589824);       // 1024 B
    float* b1    = (float*)(ws + 6 * APL + 73728 + 2359296 + 589824 + 1024);// 256 B
    f16*   wB1   = (f16*)  (ws + 6 * APL + 73728 + 2359296 + 589824 + 1280);// 49152 B

    f16* xph = a1h;                        // prepadded planes (dead region)
    f16* xpl = a1l;

    prep_all<<<dim3(690 + 8346), dim3(256), 0, stream>>>(
        c1w, bn1g, bn1b, bn1m, bn1v, blkw, blkg, blkb, blkm, blkv,
        wB, wB1, b3, b1, x, xph, xpl);

    conv1_mfma<<<dim3(12, 128), dim3(256), 0, stream>>>(xph, xpl, wB1, b1, a0h, a0l);

    conv3_mfma<0, 0><<<dim3(6, 128), dim3(256), 0, stream>>>(
        a0h, a0l, wB + 0 * 73728, b3 + 0,   nullptr, nullptr, a1h, a1l);
    conv3_mfma<1, 0><<<dim3(6, 128), dim3(256), 0, stream>>>(
        a1h, a1l, wB + 1 * 73728, b3 + 64,  a0h, a0l, a2h, a2l);
    conv3_mfma<0, 0><<<dim3(6, 128), dim3(256), 0, stream>>>(
        a2h, a2l, wB + 2 * 73728, b3 + 128, nullptr, nullptr, a1h, a1l);
    conv3_mfma<1, 1><<<dim3(6, 128), dim3(256), 0, stream>>>(
        a1h, a1l, wB + 3 * 73728, b3 + 192, a2h, a2l, a0h, a0l);  // NCHW-T out

    fc_mfma<<<dim3(576), dim3(256), 0, stream>>>(a0h, a0l, fcw, part);
    fc_reduce<<<dim3(72), dim3(256), 0, stream>>>(part, fcb, costs);
    shortest_path<<<dim3(128), dim3(192), 0, stream>>>(costs, out);
}